// Round 6
// baseline (699.578 us; speedup 1.0000x reference)
//
#include <hip/hip_runtime.h>
#include <stdint.h>

typedef _Float16 f16;
typedef _Float16 f16x8 __attribute__((ext_vector_type(8)));
typedef _Float16 f16x4 __attribute__((ext_vector_type(4)));
typedef float f32x4 __attribute__((ext_vector_type(4)));

#define S_TOK 8192
#define DDIM  512
#define L2E   1.44269504088896340736f
#define QSCALE 0.04419417382415922f   // 1/sqrt(512)
#define NSLOT 320
#define GTOT  8320                    // total KVB=32 iterations over all 64 tiles

__device__ __forceinline__ void gload_lds16(const void* g, void* l) {
  __builtin_amdgcn_global_load_lds((const __attribute__((address_space(1))) void*)g,
                                   (__attribute__((address_space(3))) void*)l, 16, 0, 0);
}

// DPP 16-lane (row) reductions — pure VALU, no LDS pipe.
template <int C>
__device__ __forceinline__ float fdpp(float x) {
  return __builtin_bit_cast(float,
      __builtin_amdgcn_update_dpp(0, __builtin_bit_cast(int, x), C, 0xF, 0xF, true));
}
__device__ __forceinline__ float rowmax16(float x) {
  x = fmaxf(x, fdpp<0xB1>(x));    // quad_perm [1,0,3,2]  (xor1)
  x = fmaxf(x, fdpp<0x4E>(x));    // quad_perm [2,3,0,1]  (xor2)
  x = fmaxf(x, fdpp<0x141>(x));   // row_half_mirror      (xor7)
  x = fmaxf(x, fdpp<0x140>(x));   // row_mirror           (xor15)
  return x;
}
__device__ __forceinline__ float rowsum16(float x) {
  x += fdpp<0xB1>(x);
  x += fdpp<0x4E>(x);
  x += fdpp<0x141>(x);
  x += fdpp<0x140>(x);
  return x;
}

// ---------------- convert f32 -> f16 (+ slot-table init) ------------------
__global__ __launch_bounds__(256) void k_convert(
    const float* __restrict__ X, const float* __restrict__ Wq,
    const float* __restrict__ Wk, const float* __restrict__ Wv,
    f16* __restrict__ Xh, f16* __restrict__ Wh, int* __restrict__ tp) {
  const int SD = S_TOK * DDIM;
  const int DD = DDIM * DDIM;
  int gi = blockIdx.x * 256 + threadIdx.x;
  if (gi < NSLOT) tp[gi] = -1;
  int i4 = gi * 4;
  if (i4 < SD) {
    f32x4 v = *(const f32x4*)(X + i4);
    f16x4 h = {(f16)v[0], (f16)v[1], (f16)v[2], (f16)v[3]};
    *(f16x4*)(Xh + i4) = h;
  } else {
    int j = i4 - SD;
    int mat = j >> 18;
    const float* src = (mat == 0) ? Wq : (mat == 1 ? Wk : Wv);
    f32x4 v = *(const f32x4*)(src + (j & (DD - 1)));
    f16x4 h = {(f16)v[0], (f16)v[1], (f16)v[2], (f16)v[3]};
    *(f16x4*)(Wh + j) = h;
  }
}

// ---------------- QKV projection ------------------------------------------
// Q,K row-major (Q pre-scaled). V packed as K=16 MFMA-B fragment PAIRS:
// block(b16 = s/16, fp = d/32) is 1KB at byte (b16*16+fp)*1024; lane l's 16B:
//   bytes 0-7 : V[b16*16 + (l>>4)*4 + j][fp*32 +      (l&15)], j=0..3
//   bytes 8-15: V[b16*16 + (l>>4)*4 + j][fp*32 + 16 + (l&15)], j=0..3
__global__ __launch_bounds__(256) void k_proj(
    const f16* __restrict__ Xh, const f16* __restrict__ Wh,
    f16* __restrict__ Qh, f16* __restrict__ Kh, f16* __restrict__ VB) {
  __shared__ __align__(16) char Al[128 * 128];
  __shared__ __align__(16) char Bl[128 * 128];
  const int tid = threadIdx.x;
  const int w = tid >> 6, lane = tid & 63;
  const int m0 = blockIdx.x * 128;
  const int n0 = blockIdx.y * 128;
  const int wr = (w >> 1) * 64;
  const int wc = (w & 1) * 64;

  f32x4 acc[4][4];
#pragma unroll
  for (int i = 0; i < 4; ++i)
#pragma unroll
    for (int j = 0; j < 4; ++j) acc[i][j] = (f32x4){0.f, 0.f, 0.f, 0.f};

  const char* Xb = (const char*)Xh;
  const char* Wb = (const char*)Wh;

  for (int kb = 0; kb < DDIM; kb += 64) {
    __syncthreads();
#pragma unroll
    for (int i = 0; i < 4; ++i) {
      int ch = w * 4 + i;
      int srow = lane >> 3;
      int scol = ((lane & 7) * 16) ^ (srow << 4);
      gload_lds16(Xb + (size_t)(m0 + ch * 8 + srow) * 1024 + kb * 2 + scol, Al + ch * 1024);
      gload_lds16(Wb + (size_t)(n0 + ch * 8 + srow) * 1024 + kb * 2 + scol, Bl + ch * 1024);
    }
    __syncthreads();
#pragma unroll
    for (int ks = 0; ks < 2; ++ks) {
      f16x8 a[4], b[4];
#pragma unroll
      for (int mf = 0; mf < 4; ++mf) {
        int row = wr + mf * 16 + (lane & 15);
        int col = (ks * 64 + ((lane >> 4) * 16)) ^ ((row & 7) << 4);
        a[mf] = *(const f16x8*)(Al + row * 128 + col);
      }
#pragma unroll
      for (int nf = 0; nf < 4; ++nf) {
        int row = wc + nf * 16 + (lane & 15);
        int col = (ks * 64 + ((lane >> 4) * 16)) ^ ((row & 7) << 4);
        b[nf] = *(const f16x8*)(Bl + row * 128 + col);
      }
#pragma unroll
      for (int mf = 0; mf < 4; ++mf)
#pragma unroll
        for (int nf = 0; nf < 4; ++nf)
          acc[mf][nf] = __builtin_amdgcn_mfma_f32_16x16x32_f16(a[mf], b[nf], acc[mf][nf], 0, 0, 0);
    }
  }
  int mat = n0 >> 9;
  int nbase = n0 & 511;
  if (mat == 2) {
#pragma unroll
    for (int mf = 0; mf < 4; ++mf) {
      int R0 = m0 + wr + mf * 16 + (lane >> 4) * 4;   // 4-aligned token row
      int b16 = R0 >> 4;
#pragma unroll
      for (int nfp = 0; nfp < 2; ++nfp) {             // frag pairs (nf = 2nfp, 2nfp+1)
        int c0 = nbase + wc + nfp * 32;               // multiple of 32
        int fp = c0 >> 5;
        f16x8 h = {(f16)acc[mf][nfp * 2][0],     (f16)acc[mf][nfp * 2][1],
                   (f16)acc[mf][nfp * 2][2],     (f16)acc[mf][nfp * 2][3],
                   (f16)acc[mf][nfp * 2 + 1][0], (f16)acc[mf][nfp * 2 + 1][1],
                   (f16)acc[mf][nfp * 2 + 1][2], (f16)acc[mf][nfp * 2 + 1][3]};
        *(f16x8*)((char*)VB + (size_t)(b16 * 16 + fp) * 1024 + lane * 16) = h;
      }
    }
  } else {
    f16* dst = (mat == 0) ? Qh : Kh;
    float scale = (mat == 0) ? QSCALE : 1.0f;
#pragma unroll
    for (int mf = 0; mf < 4; ++mf)
#pragma unroll
      for (int nf = 0; nf < 4; ++nf)
#pragma unroll
        for (int r = 0; r < 4; ++r) {
          int row = m0 + wr + mf * 16 + (lane >> 4) * 4 + r;
          int col = nbase + wc + nf * 16 + (lane & 15);
          dst[(size_t)row * DDIM + col] = (f16)(acc[mf][nf][r] * scale);
        }
  }
}

// ---------------- causal flash attention, v6 -------------------------------
// v5 skeleton (BM=128, KVB=32, 8 waves, 1 barrier/iter, split-KV) with the
// KV tile split into A/B halves below the QK^T: SM_A overlaps QK^T drain,
// PV_A (K=16 MFMA) overlaps SM_B, PV_B closes. Wave-private P bounce with
// stride-40 rows (conflict-free read).
__global__ __launch_bounds__(512, 2) void k_flash(
    const f16* __restrict__ Qh, const f16* __restrict__ Kh,
    const f16* __restrict__ VBg, f16* __restrict__ Opart,
    float* __restrict__ Mpart, float* __restrict__ Lpart,
    int* __restrict__ TilePart) {
  __shared__ __align__(16) char Kl[2][32768];   // K tile [32][512 f16] swizzled
  __shared__ __align__(16) char Vl[2][32768];   // V frag-pair blocks [32][1KB]
  __shared__ __align__(16) char Ph[8][1280];    // per-wave P bounce: 2 slots x 16 rows x 40B

  const int tid = threadIdx.x;
  const int w = tid >> 6, lane = tid & 63;
  const int l15 = lane & 15, l4 = lane >> 4;

  int bid = blockIdx.x;
  int b = (bid & 7) * 32 + (bid >> 3);          // XCD-contiguous logical id
  int g  = (GTOT * b) >> 8;
  int g1 = (GTOT * (b + 1)) >> 8;
  int t = 0;
  while (2 * (t + 1) * (t + 2) <= g) ++t;

  const char* Kb = (const char*)Kh;
  const char* Vb = (const char*)VBg;
  char* PhW = Ph[w];

#define STAGEKV(KB, BI) do {                                                   \
    _Pragma("unroll")                                                          \
    for (int i_ = 0; i_ < 4; ++i_) {                                           \
      int row_ = w * 4 + i_;                                                   \
      int scol_ = (lane * 16) ^ ((row_ & 7) << 4);                             \
      gload_lds16(Kb + (size_t)((KB) + row_) * 1024 + scol_, Kl[BI] + row_ * 1024); \
    }                                                                          \
    const char* vs_ = Vb + (size_t)(KB) * 1024;                                \
    _Pragma("unroll")                                                          \
    for (int i_ = 0; i_ < 4; ++i_) {                                           \
      int ch_ = w * 4 + i_;                                                    \
      gload_lds16(vs_ + ch_ * 1024 + lane * 16, Vl[BI] + ch_ * 1024);          \
    } } while (0)

  while (g < g1) {
    int Ct  = 2 * t * (t + 1);
    int Ct1 = 2 * (t + 1) * (t + 2);
    int gend = min(g1, Ct1);
    int n = gend - g;
    int kb0 = (g - Ct) * 32;
    int q0 = t * 128;
    int slot = b + t;

    // Q fragments: rows q0 + w*16 + l15, full D
    f16x8 qf[16];
    {
      const f16* qp = Qh + (size_t)(q0 + w * 16 + l15) * DDIM + l4 * 8;
#pragma unroll
      for (int ks = 0; ks < 16; ++ks) qf[ks] = *(const f16x8*)(qp + ks * 32);
    }
    f32x4 acc[32];
#pragma unroll
    for (int i = 0; i < 32; ++i) acc[i] = (f32x4){0.f, 0.f, 0.f, 0.f};
    float mreg[4], lreg[4];
#pragma unroll
    for (int r = 0; r < 4; ++r) { mreg[r] = -3.0e38f; lreg[r] = 0.f; }

    // prologue: stage tile 0, wait, open steady state
    STAGEKV(kb0, 0);
    asm volatile("s_waitcnt vmcnt(0)" ::: "memory");
    __builtin_amdgcn_s_barrier();

    for (int it = 0; it < n; ++it) {
      int cur = it & 1;
      if (it + 1 < n) STAGEKV(kb0 + (it + 1) * 32, cur ^ 1);

      // ---- QK^T(it): S[16 x 32] per wave over d=512 (two interleaved chains)
      const char* KlB = Kl[cur];
      f32x4 s0 = (f32x4){0.f, 0.f, 0.f, 0.f};
      f32x4 s1 = (f32x4){0.f, 0.f, 0.f, 0.f};
      __builtin_amdgcn_s_setprio(1);
#pragma unroll
      for (int ks = 0; ks < 16; ++ks) {
        int off = ks * 64 + l4 * 16;
        f16x8 kf0 = *(const f16x8*)(KlB + l15 * 1024 + (off ^ ((l15 & 7) << 4)));
        s0 = __builtin_amdgcn_mfma_f32_16x16x32_f16(qf[ks], kf0, s0, 0, 0, 0);
        f16x8 kf1 = *(const f16x8*)(KlB + (16 + l15) * 1024 + (off ^ ((l15 & 7) << 4)));
        s1 = __builtin_amdgcn_mfma_f32_16x16x32_f16(qf[ks], kf1, s1, 0, 0, 0);
      }
      __builtin_amdgcn_s_setprio(0);

      int kb = kb0 + it * 32;
      int qrb = q0 + w * 16 + l4 * 4;
      const char* VlB = Vl[cur];

      // ================= half A (kv rows kb .. kb+15) =================
      {
        float p0[4], mx[4];
        int kc = kb + l15;
#pragma unroll
        for (int r = 0; r < 4; ++r) {
          int qr = qrb + r;
          float x0 = (kc <= qr) ? s0[r] : -3.0e38f;
          p0[r] = x0;
          mx[r] = rowmax16(x0);
        }
        bool need = (mx[0] > mreg[0] + 8.f) || (mx[1] > mreg[1] + 8.f) ||
                    (mx[2] > mreg[2] + 8.f) || (mx[3] > mreg[3] + 8.f);
        if (__any(need)) {
          float alpha[4];
#pragma unroll
          for (int r = 0; r < 4; ++r) {
            float mn = fmaxf(mreg[r], mx[r]);
            alpha[r] = exp2f((mreg[r] - mn) * L2E);
            lreg[r] *= alpha[r];
            mreg[r] = mn;
          }
#pragma unroll
          for (int nf = 0; nf < 32; ++nf) {
            acc[nf][0] *= alpha[0];
            acc[nf][1] *= alpha[1];
            acc[nf][2] *= alpha[2];
            acc[nf][3] *= alpha[3];
          }
        }
#pragma unroll
        for (int r = 0; r < 4; ++r) {
          int qr = qrb + r;
          float e0 = (kc <= qr) ? exp2f((p0[r] - mreg[r]) * L2E) : 0.f;
          p0[r] = e0;
          lreg[r] += rowsum16(e0);
        }
#pragma unroll
        for (int r = 0; r < 4; ++r)
          *(f16*)(PhW + (l4 * 4 + r) * 40 + l15 * 2) = (f16)p0[r];
      }
      asm volatile("s_waitcnt lgkmcnt(0)" ::: "memory");
      __builtin_amdgcn_sched_barrier(0);
      {
        f16x4 paA = *(const f16x4*)(PhW + l15 * 40 + l4 * 8);
        __builtin_amdgcn_s_setprio(1);
#pragma unroll
        for (int fp = 0; fp < 16; ++fp) {
          f16x8 vv = *(const f16x8*)(VlB + fp * 1024 + lane * 16);
          f16x4 lo = __builtin_shufflevector(vv, vv, 0, 1, 2, 3);
          f16x4 hi = __builtin_shufflevector(vv, vv, 4, 5, 6, 7);
          acc[2 * fp]     = __builtin_amdgcn_mfma_f32_16x16x16f16(paA, lo, acc[2 * fp], 0, 0, 0);
          acc[2 * fp + 1] = __builtin_amdgcn_mfma_f32_16x16x16f16(paA, hi, acc[2 * fp + 1], 0, 0, 0);
        }
        __builtin_amdgcn_s_setprio(0);
      }

      // ================= half B (kv rows kb+16 .. kb+31) ==============
      {
        float p1[4], mx[4];
        int kc = kb + 16 + l15;
#pragma unroll
        for (int r = 0; r < 4; ++r) {
          int qr = qrb + r;
          float x1 = (kc <= qr) ? s1[r] : -3.0e38f;
          p1[r] = x1;
          mx[r] = rowmax16(x1);
        }
        bool need = (mx[0] > mreg[0] + 8.f) || (mx[1] > mreg[1] + 8.f) ||
                    (mx[2] > mreg[2] + 8.f) || (mx[3] > mreg[3] + 8.f);
        if (__any(need)) {
          float alpha[4];
#pragma unroll
          for (int r = 0; r < 4; ++r) {
            float mn = fmaxf(mreg[r], mx[r]);
            alpha[r] = exp2f((mreg[r] - mn) * L2E);
            lreg[r] *= alpha[r];
            mreg[r] = mn;
          }
#pragma unroll
          for (int nf = 0; nf < 32; ++nf) {
            acc[nf][0] *= alpha[0];
            acc[nf][1] *= alpha[1];
            acc[nf][2] *= alpha[2];
            acc[nf][3] *= alpha[3];
          }
        }
#pragma unroll
        for (int r = 0; r < 4; ++r) {
          int qr = qrb + r;
          float e1 = (kc <= qr) ? exp2f((p1[r] - mreg[r]) * L2E) : 0.f;
          p1[r] = e1;
          lreg[r] += rowsum16(e1);
        }
#pragma unroll
        for (int r = 0; r < 4; ++r)
          *(f16*)(PhW + 640 + (l4 * 4 + r) * 40 + l15 * 2) = (f16)p1[r];
      }
      asm volatile("s_waitcnt lgkmcnt(0)" ::: "memory");
      __builtin_amdgcn_sched_barrier(0);
      {
        f16x4 paB = *(const f16x4*)(PhW + 640 + l15 * 40 + l4 * 8);
        __builtin_amdgcn_s_setprio(1);
#pragma unroll
        for (int fp = 0; fp < 16; ++fp) {
          f16x8 vv = *(const f16x8*)(VlB + 16384 + fp * 1024 + lane * 16);
          f16x4 lo = __builtin_shufflevector(vv, vv, 0, 1, 2, 3);
          f16x4 hi = __builtin_shufflevector(vv, vv, 4, 5, 6, 7);
          acc[2 * fp]     = __builtin_amdgcn_mfma_f32_16x16x16f16(paB, lo, acc[2 * fp], 0, 0, 0);
          acc[2 * fp + 1] = __builtin_amdgcn_mfma_f32_16x16x16f16(paB, hi, acc[2 * fp + 1], 0, 0, 0);
        }
        __builtin_amdgcn_s_setprio(0);
      }

      if (it + 1 < n)
        asm volatile("s_waitcnt vmcnt(0)" ::: "memory");  // staged a full phase ago
      __builtin_amdgcn_s_barrier();
    }

    // ---- epilogue: all stats in-reg (DPP-reduced => uniform per row group)
    {
      float inv[4];
#pragma unroll
      for (int r = 0; r < 4; ++r) inv[r] = (lreg[r] > 0.f) ? 1.f / lreg[r] : 0.f;
      f16* op = Opart + (size_t)slot * (128 * 512);
      int rowb = w * 16 + l4 * 4;
#pragma unroll
      for (int nf = 0; nf < 32; ++nf) {
        int col = nf * 16 + l15;
#pragma unroll
        for (int r = 0; r < 4; ++r)
          op[(size_t)(rowb + r) * 512 + col] = (f16)(acc[nf][r] * inv[r]);
      }
      if (l15 == 0) {
#pragma unroll
        for (int r = 0; r < 4; ++r) {
          Mpart[slot * 128 + rowb + r] = mreg[r];
          Lpart[slot * 128 + rowb + r] = lreg[r];
        }
      }
      if (tid == 0) TilePart[slot] = t;
    }
    g = gend;
    ++t;
  }
#undef STAGEKV
}

// ---------------- combine partials -> out --------------------------------
__global__ __launch_bounds__(256) void k_reduce(
    const f16* __restrict__ Opart, const float* __restrict__ Mpart,
    const float* __restrict__ Lpart, const int* __restrict__ TilePart,
    float* __restrict__ out) {
  __shared__ int tp[NSLOT];
  __shared__ int sl[16];
  __shared__ int scnt;
  int tid = threadIdx.x;
  int t = blockIdx.x >> 2, rg = blockIdx.x & 3;
  for (int s = tid; s < NSLOT; s += 256) tp[s] = TilePart[s];
  __syncthreads();
  if (tid == 0) {
    int c = 0;
    for (int s = 0; s < NSLOT; ++s)
      if (tp[s] == t && c < 16) sl[c++] = s;
    scnt = c;
  }
  __syncthreads();
  int cnt = scnt;
  int rowIn = rg * 32 + (tid >> 3);
  int row = t * 128 + rowIn;
  int col0 = (tid & 7) * 64;

  float M = -3.0e38f;
  for (int i = 0; i < cnt; ++i) M = fmaxf(M, Mpart[sl[i] * 128 + rowIn]);
  float a[64];
#pragma unroll
  for (int j = 0; j < 64; ++j) a[j] = 0.f;
  float denom = 0.f;
  for (int i = 0; i < cnt; ++i) {
    int s = sl[i];
    float m = Mpart[s * 128 + rowIn];
    float l = Lpart[s * 128 + rowIn];
    float wgt = exp2f((m - M) * L2E) * l;
    denom += wgt;
    const f16* op = Opart + (size_t)s * 65536 + rowIn * 512 + col0;
#pragma unroll
    for (int v = 0; v < 8; ++v) {
      f16x8 x = *(const f16x8*)(op + v * 8);
#pragma unroll
      for (int j = 0; j < 8; ++j) a[v * 8 + j] += wgt * (float)x[j];
    }
  }
  float inv = (denom > 0.f) ? 1.f / denom : 0.f;
  float* o = out + (size_t)row * 512 + col0;
#pragma unroll
  for (int j = 0; j < 64; ++j) o[j] = a[j] * inv;
}

extern "C" void kernel_launch(void* const* d_in, const int* in_sizes, int n_in,
                              void* d_out, int out_size, void* d_ws, size_t ws_size,
                              hipStream_t stream) {
  const float* X  = (const float*)d_in[0];
  const float* Wq = (const float*)d_in[2];
  const float* Wk = (const float*)d_in[3];
  const float* Wv = (const float*)d_in[4];
  float* out = (float*)d_out;

  char* ws = (char*)d_ws;
  f16*   Opart = (f16*)(ws);                               // 40 MiB
  float* Mpart = (float*)(ws + (40u << 20));               // 160 KiB
  float* Lpart = (float*)(ws + (41u << 20));               // 160 KiB
  int*   TileP = (int*)(ws + (42u << 20));                 // 1.25 KiB
  f16* Qh = (f16*)(ws + (43u << 20));                      // 8 MiB (pre-scaled)
  f16* Kh = (f16*)(ws + (51u << 20));                      // 8 MiB
  f16* VB = (f16*)(ws + (59u << 20));                      // 8 MiB packed frag pairs
  f16* Xh = (f16*)(ws + (67u << 20));                      // 8 MiB
  f16* Wh = (f16*)(ws + (75u << 20));                      // 1.5 MiB

  k_convert<<<4864, 256, 0, stream>>>(X, Wq, Wk, Wv, Xh, Wh, TileP);
  dim3 gp(64, 12);
  k_proj<<<gp, 256, 0, stream>>>(Xh, Wh, Qh, Kh, VB);
  k_flash<<<256, 512, 0, stream>>>(Qh, Kh, VB, Opart, Mpart, Lpart, TileP);
  k_reduce<<<256, 256, 0, stream>>>(Opart, Mpart, Lpart, TileP, out);
}